// Round 1
// baseline (1995.733 us; speedup 1.0000x reference)
//
#include <hip/hip_runtime.h>

#define EMB   1024
#define SEQ   2048
#define BATCH 4
#define HEADS 16
#define HDIM  64
#define MTOT  (BATCH * SEQ)  // 8192

// ---------------------------------------------------------------------------
// GEMM: C = A[M x EMB] @ W[EMB x EMB] + bias
// grid.z selects (W,bias,C) triple; head_split=1 writes C in [B,H,N,D] layout.
// 64x64 output tile per block, 256 threads, 4x4 micro-tile, k-chunk 16.
// LDS: both operands stored [k][m]/[k][n] so inner loop is 2x ds_read_b128.
// ---------------------------------------------------------------------------
__global__ __launch_bounds__(256) void gemm_kernel(
    const float* __restrict__ A,
    const float* __restrict__ W0, const float* __restrict__ W1, const float* __restrict__ W2,
    const float* __restrict__ b0, const float* __restrict__ b1, const float* __restrict__ b2,
    float* __restrict__ C0, float* __restrict__ C1, float* __restrict__ C2,
    int head_split)
{
    const int z = blockIdx.z;
    const float* __restrict__ W    = (z == 0) ? W0 : ((z == 1) ? W1 : W2);
    const float* __restrict__ bias = (z == 0) ? b0 : ((z == 1) ? b1 : b2);
    float* __restrict__ C          = (z == 0) ? C0 : ((z == 1) ? C1 : C2);

    __shared__ float As[16][68];  // [k][m], padded
    __shared__ float Bs[16][68];  // [k][n], padded

    const int t  = threadIdx.x;
    const int tx = t & 15;        // output col group (4 cols)
    const int ty = t >> 4;        // output row group (4 rows)
    const int m0 = blockIdx.x * 64;
    const int e0 = blockIdx.y * 64;

    // staging assignments
    const int ar  = t >> 2;          // A row 0..63
    const int ac4 = (t & 3) * 4;     // A col chunk 0/4/8/12
    const int bk  = t >> 4;          // B k-row 0..15
    const int bc4 = (t & 15) * 4;    // B col chunk

    float acc[4][4] = {};

    for (int k0 = 0; k0 < EMB; k0 += 16) {
        float4 av = *(const float4*)(A + (size_t)(m0 + ar) * EMB + (k0 + ac4));
        float4 bv = *(const float4*)(W + (size_t)(k0 + bk) * EMB + (e0 + bc4));
        // A transposed into [k][m]
        As[ac4 + 0][ar] = av.x;
        As[ac4 + 1][ar] = av.y;
        As[ac4 + 2][ar] = av.z;
        As[ac4 + 3][ar] = av.w;
        // B natural [k][n]
        *(float4*)&Bs[bk][bc4] = bv;
        __syncthreads();

#pragma unroll
        for (int kk = 0; kk < 16; ++kk) {
            float4 aa = *(const float4*)&As[kk][ty * 4];
            float4 bb = *(const float4*)&Bs[kk][tx * 4];
            float a[4] = {aa.x, aa.y, aa.z, aa.w};
            float b[4] = {bb.x, bb.y, bb.z, bb.w};
#pragma unroll
            for (int i = 0; i < 4; ++i)
#pragma unroll
                for (int j = 0; j < 4; ++j)
                    acc[i][j] = fmaf(a[i], b[j], acc[i][j]);
        }
        __syncthreads();
    }

    // epilogue
    float4 bvv = *(const float4*)(bias + e0 + tx * 4);
    const float bj[4] = {bvv.x, bvv.y, bvv.z, bvv.w};

#pragma unroll
    for (int i = 0; i < 4; ++i) {
        const int row = ty * 4 + i;
        const int m   = m0 + row;
        float4 o;
        o.x = acc[i][0] + bj[0];
        o.y = acc[i][1] + bj[1];
        o.z = acc[i][2] + bj[2];
        o.w = acc[i][3] + bj[3];
        size_t addr;
        if (head_split) {
            const int bidx = m >> 11;       // / SEQ
            const int n    = m & (SEQ - 1);
            const int h    = e0 >> 6;       // tile spans exactly one head
            addr = (((size_t)(bidx * HEADS + h)) * SEQ + n) * HDIM + tx * 4;
        } else {
            addr = (size_t)m * EMB + e0 + tx * 4;
        }
        *(float4*)(C + addr) = o;
    }
}

// ---------------------------------------------------------------------------
// Flash-style attention: one block per (b*h, 64-row Q tile). 256 threads.
// Online softmax, K/V tiles of 64, P via LDS. Writes att_out in [B,N,E].
// scale = 1/sqrt(EMB) = 1/32 (reference scales by sqrt(emb), not head dim!)
// ---------------------------------------------------------------------------
__global__ __launch_bounds__(256) void attn_kernel(
    const float* __restrict__ q, const float* __restrict__ k,
    const float* __restrict__ v, float* __restrict__ att)
{
    __shared__ float Qs[64][68];  // [d][qrow]
    __shared__ float Ks[64][68];  // [d][krow]
    __shared__ float Vs[64][68];  // [krow][d]
    __shared__ float Ps[64][68];  // [krow][qrow]

    const int t   = threadIdx.x;
    const int tx  = t & 15;
    const int ty  = t >> 4;
    const int qr0 = blockIdx.x * 64;
    const int bh  = blockIdx.y;
    const size_t base = (size_t)bh * SEQ * HDIM;

    const int sr  = t >> 2;          // staging row 0..63
    const int sc4 = (t & 3) * 4;     // staging col chunk

    // stage Q transposed (once)
#pragma unroll
    for (int p = 0; p < 4; ++p) {
        const int c = sc4 + p * 16;
        float4 qv = *(const float4*)(q + base + (size_t)(qr0 + sr) * HDIM + c);
        Qs[c + 0][sr] = qv.x;
        Qs[c + 1][sr] = qv.y;
        Qs[c + 2][sr] = qv.z;
        Qs[c + 3][sr] = qv.w;
    }

    float o[4][4] = {};
    float m_i[4], l_i[4];
#pragma unroll
    for (int i = 0; i < 4; ++i) { m_i[i] = -1e30f; l_i[i] = 0.0f; }

    for (int kt = 0; kt < SEQ / 64; ++kt) {
        __syncthreads();  // prior PV done before restaging K/V
        const int kr0 = kt * 64;
#pragma unroll
        for (int p = 0; p < 4; ++p) {
            const int c = sc4 + p * 16;
            float4 kv = *(const float4*)(k + base + (size_t)(kr0 + sr) * HDIM + c);
            Ks[c + 0][sr] = kv.x;
            Ks[c + 1][sr] = kv.y;
            Ks[c + 2][sr] = kv.z;
            Ks[c + 3][sr] = kv.w;
            float4 vv = *(const float4*)(v + base + (size_t)(kr0 + sr) * HDIM + c);
            *(float4*)&Vs[sr][c] = vv;
        }
        __syncthreads();

        // S = Q Kt  (4x4 micro-tile per thread)
        float s[4][4] = {};
#pragma unroll 16
        for (int d = 0; d < 64; ++d) {
            float4 qa = *(const float4*)&Qs[d][ty * 4];
            float4 kb = *(const float4*)&Ks[d][tx * 4];
            float a[4] = {qa.x, qa.y, qa.z, qa.w};
            float b[4] = {kb.x, kb.y, kb.z, kb.w};
#pragma unroll
            for (int i = 0; i < 4; ++i)
#pragma unroll
                for (int j = 0; j < 4; ++j)
                    s[i][j] = fmaf(a[i], b[j], s[i][j]);
        }

        // online softmax per row; row = 16 lanes (fixed ty), shuffle width 16
#pragma unroll
        for (int i = 0; i < 4; ++i) {
            float sm = -1e30f;
#pragma unroll
            for (int j = 0; j < 4; ++j) {
                s[i][j] *= 0.03125f;  // 1/sqrt(1024)
                sm = fmaxf(sm, s[i][j]);
            }
            for (int off = 1; off < 16; off <<= 1)
                sm = fmaxf(sm, __shfl_xor(sm, off, 16));
            const float mn    = fmaxf(m_i[i], sm);
            const float alpha = __expf(m_i[i] - mn);
            float ps = 0.0f;
#pragma unroll
            for (int j = 0; j < 4; ++j) {
                s[i][j] = __expf(s[i][j] - mn);
                ps += s[i][j];
            }
            for (int off = 1; off < 16; off <<= 1)
                ps += __shfl_xor(ps, off, 16);
            l_i[i] = l_i[i] * alpha + ps;
            m_i[i] = mn;
#pragma unroll
            for (int j = 0; j < 4; ++j) {
                o[i][j] *= alpha;
                Ps[tx * 4 + j][ty * 4 + i] = s[i][j];  // P transposed [krow][qrow]
            }
        }
        __syncthreads();

        // O += P V
#pragma unroll 16
        for (int jj = 0; jj < 64; ++jj) {
            float4 pa = *(const float4*)&Ps[jj][ty * 4];
            float4 vb = *(const float4*)&Vs[jj][tx * 4];
            float a[4] = {pa.x, pa.y, pa.z, pa.w};
            float b[4] = {vb.x, vb.y, vb.z, vb.w};
#pragma unroll
            for (int i = 0; i < 4; ++i)
#pragma unroll
                for (int j = 0; j < 4; ++j)
                    o[i][j] = fmaf(a[i], b[j], o[i][j]);
        }
    }

    // epilogue: normalize, merge heads -> [B, N, E]
    const int b = bh >> 4;
    const int h = bh & 15;
#pragma unroll
    for (int i = 0; i < 4; ++i) {
        const float inv = 1.0f / l_i[i];
        float4 ov;
        ov.x = o[i][0] * inv;
        ov.y = o[i][1] * inv;
        ov.z = o[i][2] * inv;
        ov.w = o[i][3] * inv;
        const size_t addr =
            ((size_t)b * SEQ + qr0 + ty * 4 + i) * EMB + h * HDIM + tx * 4;
        *(float4*)(att + addr) = ov;
    }
}

extern "C" void kernel_launch(void* const* d_in, const int* in_sizes, int n_in,
                              void* d_out, int out_size, void* d_ws, size_t ws_size,
                              hipStream_t stream)
{
    const float* x  = (const float*)d_in[0];
    const float* Wq = (const float*)d_in[1];
    const float* bq = (const float*)d_in[2];
    const float* Wk = (const float*)d_in[3];
    const float* bk = (const float*)d_in[4];
    const float* Wv = (const float*)d_in[5];
    const float* bv = (const float*)d_in[6];
    const float* Wo = (const float*)d_in[7];
    const float* bo = (const float*)d_in[8];
    float* out = (float*)d_out;

    float* ws = (float*)d_ws;
    const size_t SZ = (size_t)BATCH * HEADS * SEQ * HDIM;  // 8388608 elements
    float* qb   = ws;
    float* kb   = ws + SZ;
    float* vb   = ws + 2 * SZ;
    float* attb = ws + 3 * SZ;

    // 1) fused QKV projections, head-split output [B,H,N,D]
    dim3 g1(MTOT / 64, EMB / 64, 3);
    gemm_kernel<<<g1, 256, 0, stream>>>(x, Wq, Wk, Wv, bq, bk, bv, qb, kb, vb, 1);

    // 2) attention -> [B,N,E]
    dim3 g2(SEQ / 64, BATCH * HEADS, 1);
    attn_kernel<<<g2, 256, 0, stream>>>(qb, kb, vb, attb);

    // 3) output projection -> d_out
    dim3 g3(MTOT / 64, EMB / 64, 1);
    gemm_kernel<<<g3, 256, 0, stream>>>(attb, Wo, Wo, Wo, bo, bo, bo, out, out, out, 0);
}

// Round 2
// 426.787 us; speedup vs baseline: 4.6762x; 4.6762x over previous
//
#include <hip/hip_runtime.h>

#define EMB   1024
#define SEQ   2048
#define BATCH 4
#define HEADS 16
#define HDIM  64
#define MTOT  8192

typedef __bf16 bf16x8 __attribute__((ext_vector_type(8)));
typedef float  fx4    __attribute__((ext_vector_type(4)));

__device__ __forceinline__ unsigned short f2bf(float f) {
    unsigned u = __builtin_bit_cast(unsigned, f);
    u += 0x7fffu + ((u >> 16) & 1u);   // RNE
    return (unsigned short)(u >> 16);
}
__device__ __forceinline__ float bf2f(unsigned short h) {
    unsigned u = ((unsigned)h) << 16;
    return __builtin_bit_cast(float, u);
}

#define AS1 __attribute__((address_space(1)))
#define AS3 __attribute__((address_space(3)))
__device__ __forceinline__ void glds16(const void* g, void* l) {
    __builtin_amdgcn_global_load_lds((AS1 void*)g, (AS3 void*)l, 16, 0, 0);
}

// ---------------------------------------------------------------------------
// x [8192x1024] fp32 -> bf16 (same layout)
// ---------------------------------------------------------------------------
__global__ __launch_bounds__(256) void cvt_x_kernel(const float* __restrict__ x,
                                                    unsigned short* __restrict__ xb)
{
    const int idx = (blockIdx.x * 256 + threadIdx.x) * 4;
    const float4 v = *(const float4*)(x + idx);
    ushort4 o;
    o.x = f2bf(v.x); o.y = f2bf(v.y); o.z = f2bf(v.z); o.w = f2bf(v.w);
    *(ushort4*)(xb + idx) = o;
}

// ---------------------------------------------------------------------------
// W [K][N] fp32 -> Wt [N][K] bf16 (transpose), 4 matrices via grid.z
// ---------------------------------------------------------------------------
__global__ __launch_bounds__(256) void cvt_w_kernel(
    const float* __restrict__ w0, const float* __restrict__ w1,
    const float* __restrict__ w2, const float* __restrict__ w3,
    unsigned short* __restrict__ o0, unsigned short* __restrict__ o1,
    unsigned short* __restrict__ o2, unsigned short* __restrict__ o3)
{
    const int z = blockIdx.z;
    const float* W = z == 0 ? w0 : (z == 1 ? w1 : (z == 2 ? w2 : w3));
    unsigned short* O = z == 0 ? o0 : (z == 1 ? o1 : (z == 2 ? o2 : o3));

    __shared__ float Ws[64][65];
    const int t  = threadIdx.x;
    const int k0 = blockIdx.x * 64, n0 = blockIdx.y * 64;
#pragma unroll
    for (int p = 0; p < 4; ++p) {
        const int row = p * 16 + (t >> 4);
        const int col = (t & 15) * 4;
        const float4 v = *(const float4*)(W + (size_t)(k0 + row) * EMB + n0 + col);
        Ws[row][col]     = v.x; Ws[row][col + 1] = v.y;
        Ws[row][col + 2] = v.z; Ws[row][col + 3] = v.w;
    }
    __syncthreads();
    const int nn = t >> 2;
    const int kb = (t & 3) * 16;
#pragma unroll
    for (int q = 0; q < 2; ++q) {
        const int kk = kb + q * 8;
        ushort4 u0, u1;
        u0.x = f2bf(Ws[kk + 0][nn]); u0.y = f2bf(Ws[kk + 1][nn]);
        u0.z = f2bf(Ws[kk + 2][nn]); u0.w = f2bf(Ws[kk + 3][nn]);
        u1.x = f2bf(Ws[kk + 4][nn]); u1.y = f2bf(Ws[kk + 5][nn]);
        u1.z = f2bf(Ws[kk + 6][nn]); u1.w = f2bf(Ws[kk + 7][nn]);
        *(ushort4*)(O + (size_t)(n0 + nn) * EMB + k0 + kk)     = u0;
        *(ushort4*)(O + (size_t)(n0 + nn) * EMB + k0 + kk + 4) = u1;
    }
}

// ---------------------------------------------------------------------------
// bf16 MFMA GEMM (m97 structure): C[m][e] = sum_k A[m][k] * Bt[e][k] + bias[e]
// 128x128 tile / 256 thr / BK=32 / global_load_lds 16B staging.
// mode 0: z selects Q/K/V; Q,K -> [B,H,N,D] bf16, V -> [B,H,D,N] bf16.
// mode 1: fp32 out [M][E].
// ---------------------------------------------------------------------------
__global__ __launch_bounds__(256) void gemm_bf16_kernel(
    const unsigned short* __restrict__ Ag,
    const unsigned short* __restrict__ B0, const unsigned short* __restrict__ B1,
    const unsigned short* __restrict__ B2,
    const float* __restrict__ bias0, const float* __restrict__ bias1,
    const float* __restrict__ bias2,
    void* out0, void* out1, void* out2, int mode)
{
    const int z = blockIdx.z;
    const unsigned short* __restrict__ Bg = z == 0 ? B0 : (z == 1 ? B1 : B2);
    const float* __restrict__ bias = z == 0 ? bias0 : (z == 1 ? bias1 : bias2);
    void* outp = z == 0 ? out0 : (z == 1 ? out1 : out2);

    __shared__ unsigned short As[128][32];
    __shared__ unsigned short Bs[128][32];

    const int t    = threadIdx.x;
    const int w    = t >> 6;
    const int lane = t & 63;
    const int low4 = lane & 15;
    const int quad = lane >> 4;
    const int m0 = blockIdx.x * 128;
    const int e0 = blockIdx.y * 128;
    const int wr = (w & 1) * 64;
    const int wc = (w >> 1) * 64;

    const int srow = w * 32 + (lane >> 2);   // staging row (+0 / +16)
    const int scol = (lane & 3) * 8;         // staging k-chunk (8 bf16 = 16B)

    fx4 acc[4][4] = {};

    for (int k0 = 0; k0 < EMB; k0 += 32) {
        __syncthreads();
        glds16(Ag + (size_t)(m0 + srow) * EMB + k0 + scol,      &As[w * 32][0]);
        glds16(Ag + (size_t)(m0 + srow + 16) * EMB + k0 + scol, &As[w * 32 + 16][0]);
        glds16(Bg + (size_t)(e0 + srow) * EMB + k0 + scol,      &Bs[w * 32][0]);
        glds16(Bg + (size_t)(e0 + srow + 16) * EMB + k0 + scol, &Bs[w * 32 + 16][0]);
        __syncthreads();

        bf16x8 af[4], bfr[4];
#pragma unroll
        for (int i = 0; i < 4; ++i) {
            af[i]  = *(const bf16x8*)&As[wr + i * 16 + low4][quad * 8];
            bfr[i] = *(const bf16x8*)&Bs[wc + i * 16 + low4][quad * 8];
        }
#pragma unroll
        for (int i = 0; i < 4; ++i)
#pragma unroll
            for (int j = 0; j < 4; ++j)
                acc[i][j] = __builtin_amdgcn_mfma_f32_16x16x32_bf16(af[i], bfr[j], acc[i][j], 0, 0, 0);
    }

    float bv[4];
#pragma unroll
    for (int j = 0; j < 4; ++j) bv[j] = bias[e0 + wc + j * 16 + low4];

#pragma unroll
    for (int i = 0; i < 4; ++i) {
#pragma unroll
        for (int j = 0; j < 4; ++j) {
#pragma unroll
            for (int rr = 0; rr < 4; ++rr) {
                const int m = m0 + wr + i * 16 + quad * 4 + rr;
                const int e = e0 + wc + j * 16 + low4;
                const float val = acc[i][j][rr] + bv[j];
                if (mode == 1) {
                    ((float*)outp)[(size_t)m * EMB + e] = val;
                } else {
                    const int bb = m >> 11, n = m & (SEQ - 1);
                    const int hh = e >> 6, d = e & 63;
                    unsigned short* o = (unsigned short*)outp;
                    if (z <= 1)
                        o[(((size_t)(bb * HEADS + hh)) * SEQ + n) * HDIM + d] = f2bf(val);
                    else
                        o[(((size_t)(bb * HEADS + hh)) * HDIM + d) * SEQ + n] = f2bf(val);
                }
            }
        }
    }
}

// ---------------------------------------------------------------------------
// MFMA flash attention. Block = (64 q-rows, one b*h). 4 waves, 16 q-rows/wave.
// Q,K: [B,H,N,D] bf16; V: [B,H,D,N] bf16. Out: att [B*N][EMB] bf16.
// scale 1/sqrt(EMB) = 1/32.
// ---------------------------------------------------------------------------
__global__ __launch_bounds__(256) void attn_mfma_kernel(
    const unsigned short* __restrict__ qg, const unsigned short* __restrict__ kg,
    const unsigned short* __restrict__ vg, unsigned short* __restrict__ attb)
{
    __shared__ unsigned short Ks[64][72];      // [kv][d]  (+8 pad)
    __shared__ unsigned short Vs[64][72];      // [d][kv]  (+8 pad)
    __shared__ unsigned short Ps[4][16][72];   // per-wave [q][kv]

    const int t    = threadIdx.x;
    const int w    = t >> 6;
    const int lane = t & 63;
    const int low4 = lane & 15;
    const int quad = lane >> 4;
    const int q0   = blockIdx.x * 64;
    const int bh   = blockIdx.y;
    const size_t base = (size_t)bh * SEQ * HDIM;   // same element count for q/k/v

    // resident Q A-fragments (16 q-rows per wave, k-chunks of 32 over D=64)
    bf16x8 aq0, aq1;
    {
        const size_t qrow = base + (size_t)(q0 + w * 16 + low4) * HDIM;
        aq0 = *(const bf16x8*)(qg + qrow + quad * 8);
        aq1 = *(const bf16x8*)(qg + qrow + 32 + quad * 8);
    }

    fx4 o_acc[4] = {};
    float m_i[4], l_i[4];
#pragma unroll
    for (int r = 0; r < 4; ++r) { m_i[r] = -1e30f; l_i[r] = 0.0f; }

    const int ch0 = t, ch1 = t + 256;          // staging chunk ids (512 of 16B)
    const fx4 fzero = {0.f, 0.f, 0.f, 0.f};

    for (int kv0 = 0; kv0 < SEQ; kv0 += 64) {
        __syncthreads();
        {
            const int r0 = ch0 >> 3, c0 = (ch0 & 7) * 8;
            const int r1 = ch1 >> 3, c1 = (ch1 & 7) * 8;
            *(bf16x8*)&Ks[r0][c0] = *(const bf16x8*)(kg + base + (size_t)(kv0 + r0) * HDIM + c0);
            *(bf16x8*)&Ks[r1][c1] = *(const bf16x8*)(kg + base + (size_t)(kv0 + r1) * HDIM + c1);
            *(bf16x8*)&Vs[r0][c0] = *(const bf16x8*)(vg + base + (size_t)r0 * SEQ + kv0 + c0);
            *(bf16x8*)&Vs[r1][c1] = *(const bf16x8*)(vg + base + (size_t)r1 * SEQ + kv0 + c1);
        }
        __syncthreads();

        // S = Q K^T  (4 kv-subtiles of 16)
        fx4 s_acc[4];
#pragma unroll
        for (int tt = 0; tt < 4; ++tt) {
            bf16x8 b0 = *(const bf16x8*)&Ks[tt * 16 + low4][quad * 8];
            bf16x8 b1 = *(const bf16x8*)&Ks[tt * 16 + low4][32 + quad * 8];
            s_acc[tt] = __builtin_amdgcn_mfma_f32_16x16x32_bf16(aq0, b0, fzero, 0, 0, 0);
            s_acc[tt] = __builtin_amdgcn_mfma_f32_16x16x32_bf16(aq1, b1, s_acc[tt], 0, 0, 0);
        }
#pragma unroll
        for (int tt = 0; tt < 4; ++tt) s_acc[tt] *= 0.03125f;   // 1/sqrt(1024)

        // online softmax; q-row = quad*4+r, reduce over 16 lanes (same quad)
#pragma unroll
        for (int r = 0; r < 4; ++r) {
            float mx = fmaxf(fmaxf(s_acc[0][r], s_acc[1][r]),
                             fmaxf(s_acc[2][r], s_acc[3][r]));
            for (int off = 1; off < 16; off <<= 1)
                mx = fmaxf(mx, __shfl_xor(mx, off, 16));
            const float mn = fmaxf(m_i[r], mx);
            const float al = __expf(m_i[r] - mn);
            float ps = 0.f, pv[4];
#pragma unroll
            for (int tt = 0; tt < 4; ++tt) { pv[tt] = __expf(s_acc[tt][r] - mn); ps += pv[tt]; }
            for (int off = 1; off < 16; off <<= 1)
                ps += __shfl_xor(ps, off, 16);
            l_i[r] = l_i[r] * al + ps;
            m_i[r] = mn;
#pragma unroll
            for (int t2 = 0; t2 < 4; ++t2) o_acc[t2][r] *= al;
#pragma unroll
            for (int tt = 0; tt < 4; ++tt)
                Ps[w][quad * 4 + r][tt * 16 + low4] = f2bf(pv[tt]);
        }

        // O += P V   (intra-wave LDS: DS ops are in-order per wave, no barrier)
        bf16x8 p0 = *(const bf16x8*)&Ps[w][low4][quad * 8];
        bf16x8 p1 = *(const bf16x8*)&Ps[w][low4][32 + quad * 8];
#pragma unroll
        for (int t2 = 0; t2 < 4; ++t2) {
            bf16x8 v0 = *(const bf16x8*)&Vs[t2 * 16 + low4][quad * 8];
            bf16x8 v1 = *(const bf16x8*)&Vs[t2 * 16 + low4][32 + quad * 8];
            o_acc[t2] = __builtin_amdgcn_mfma_f32_16x16x32_bf16(p0, v0, o_acc[t2], 0, 0, 0);
            o_acc[t2] = __builtin_amdgcn_mfma_f32_16x16x32_bf16(p1, v1, o_acc[t2], 0, 0, 0);
        }
    }

    // epilogue: merge heads -> att [B*N][EMB] bf16
    const int bb = bh >> 4, hh = bh & 15;
#pragma unroll
    for (int r = 0; r < 4; ++r) {
        const float inv = 1.0f / l_i[r];
        const size_t m = (size_t)bb * SEQ + q0 + w * 16 + quad * 4 + r;
#pragma unroll
        for (int t2 = 0; t2 < 4; ++t2) {
            const int e = hh * HDIM + t2 * 16 + low4;
            attb[m * EMB + e] = f2bf(o_acc[t2][r] * inv);
        }
    }
}

extern "C" void kernel_launch(void* const* d_in, const int* in_sizes, int n_in,
                              void* d_out, int out_size, void* d_ws, size_t ws_size,
                              hipStream_t stream)
{
    const float* x  = (const float*)d_in[0];
    const float* Wq = (const float*)d_in[1];
    const float* bq = (const float*)d_in[2];
    const float* Wk = (const float*)d_in[3];
    const float* bk = (const float*)d_in[4];
    const float* Wv = (const float*)d_in[5];
    const float* bv = (const float*)d_in[6];
    const float* Wo = (const float*)d_in[7];
    const float* bo = (const float*)d_in[8];

    unsigned short* ws  = (unsigned short*)d_ws;
    unsigned short* xb  = ws;                  // 8388608
    unsigned short* wqt = xb + 8388608;        // 1048576 each
    unsigned short* wkt = wqt + 1048576;
    unsigned short* wvt = wkt + 1048576;
    unsigned short* wot = wvt + 1048576;
    unsigned short* qb  = wot + 1048576;       // 8388608 each
    unsigned short* kbuf = qb + 8388608;
    unsigned short* vtb  = kbuf + 8388608;
    unsigned short* attb = vtb + 8388608;      // total 92.3 MB

    cvt_x_kernel<<<8192, 256, 0, stream>>>(x, xb);
    cvt_w_kernel<<<dim3(16, 16, 4), 256, 0, stream>>>(Wq, Wk, Wv, Wo, wqt, wkt, wvt, wot);

    gemm_bf16_kernel<<<dim3(64, 8, 3), 256, 0, stream>>>(
        xb, wqt, wkt, wvt, bq, bk, bv, qb, kbuf, vtb, 0);

    attn_mfma_kernel<<<dim3(32, 64), 256, 0, stream>>>(qb, kbuf, vtb, attb);

    gemm_bf16_kernel<<<dim3(64, 8, 1), 256, 0, stream>>>(
        attb, wot, wot, wot, bo, bo, bo, d_out, d_out, d_out, 1);
}